// Round 4
// baseline (1025.512 us; speedup 1.0000x reference)
//
#include <hip/hip_runtime.h>
#include <hip/hip_bf16.h>

typedef short bf16x8 __attribute__((ext_vector_type(8)));
typedef float f32x4 __attribute__((ext_vector_type(4)));
typedef unsigned short u16x8 __attribute__((ext_vector_type(8)));

#define DEVI static __device__ __forceinline__

constexpr int Bb = 4, Hh = 16, Ss = 2048, Dd = 64;
constexpr int BH = Bb * Hh;
constexpr float SCALE = 0.125f;                    // 1/sqrt(64)
constexpr long QKV_ELEMS = (long)BH * Ss * Dd;     // 8,388,608
constexpr long MASK_ELEMS = (long)BH * Ss * Ss;    // 268,435,456

DEVI unsigned short f2bf(float f) {
  __hip_bfloat16 h = __float2bfloat16(f);
  unsigned short u;
  __builtin_memcpy(&u, &h, 2);
  return u;
}

DEVI bf16x8 cvt8(const float* p) {
  float4 a = *reinterpret_cast<const float4*>(p);
  float4 b = *reinterpret_cast<const float4*>(p + 4);
  bf16x8 r;
  r[0] = (short)f2bf(a.x); r[1] = (short)f2bf(a.y); r[2] = (short)f2bf(a.z); r[3] = (short)f2bf(a.w);
  r[4] = (short)f2bf(b.x); r[5] = (short)f2bf(b.y); r[6] = (short)f2bf(b.z); r[7] = (short)f2bf(b.w);
  return r;
}

// ---------------- prologue: mask int32 -> 1 bit/elem ----------------
__global__ __launch_bounds__(256) void bitpack(const int* __restrict__ mask,
                                               unsigned long long* __restrict__ bits)
{
  const long wid = (((long)blockIdx.x * 256 + threadIdx.x) >> 6);
  const int lane = threadIdx.x & 63;
  const long NW = ((long)gridDim.x * 256) >> 6;
  for (long W = wid; W < (MASK_ELEMS >> 8); W += NW) {
    const int* p = mask + (W << 8) + lane;
    const unsigned long long b0 = __ballot(__builtin_nontemporal_load(p) != 0);
    const unsigned long long b1 = __ballot(__builtin_nontemporal_load(p + 64) != 0);
    const unsigned long long b2 = __ballot(__builtin_nontemporal_load(p + 128) != 0);
    const unsigned long long b3 = __ballot(__builtin_nontemporal_load(p + 192) != 0);
    if (lane == 0) {
      ulonglong4 o; o.x = b0; o.y = b1; o.z = b2; o.w = b3;
      *reinterpret_cast<ulonglong4*>(bits + (W << 2)) = o;
    }
  }
}

// ---------------- prologue: fp32 -> bf16 casts ----------------
__global__ __launch_bounds__(256) void cvt_qk(const float* __restrict__ q, const float* __restrict__ k,
                                              unsigned short* __restrict__ qb, unsigned short* __restrict__ kb)
{
  const long i = ((long)blockIdx.x * 256 + threadIdx.x) * 4;
  if (i >= QKV_ELEMS) return;
  const float4 a = *reinterpret_cast<const float4*>(q + i);
  ushort4 oa; oa.x = f2bf(a.x); oa.y = f2bf(a.y); oa.z = f2bf(a.z); oa.w = f2bf(a.w);
  *reinterpret_cast<ushort4*>(qb + i) = oa;
  const float4 b = *reinterpret_cast<const float4*>(k + i);
  ushort4 ob; ob.x = f2bf(b.x); ob.y = f2bf(b.y); ob.z = f2bf(b.z); ob.w = f2bf(b.w);
  *reinterpret_cast<ushort4*>(kb + i) = ob;
}

// V [bh][s][d] fp32 -> Vt [bh][d][s] bf16
__global__ __launch_bounds__(256) void cvt_vt(const float* __restrict__ v, unsigned short* __restrict__ vt)
{
  __shared__ float tile[64][65];
  const int bh = blockIdx.x >> 5;
  const int s0 = (blockIdx.x & 31) << 6;
  const int t  = threadIdx.x;
  {
    const int c = (t & 15) << 2;
    const float* src = v + ((long)bh * Ss + s0) * Dd;
    for (int rr = (t >> 4); rr < 64; rr += 16) {
      const float4 a = *reinterpret_cast<const float4*>(src + rr * Dd + c);
      tile[rr][c] = a.x; tile[rr][c + 1] = a.y; tile[rr][c + 2] = a.z; tile[rr][c + 3] = a.w;
    }
  }
  __syncthreads();
  {
    const int d  = t >> 2;
    const int sc = (t & 3) << 4;
    unsigned short* dst = vt + ((long)bh * Dd + d) * Ss + s0 + sc;
    u16x8 v0, v1;
#pragma unroll
    for (int j = 0; j < 8; ++j) v0[j] = f2bf(tile[sc + j][d]);
#pragma unroll
    for (int j = 0; j < 8; ++j) v1[j] = f2bf(tile[sc + 8 + j][d]);
    *reinterpret_cast<u16x8*>(dst)     = v0;
    *reinterpret_cast<u16x8*>(dst + 8) = v1;
  }
}

// ---------------- main fused attention (two-pass recompute) ----------------
// Block = 16 q-rows of one (b,h), 4 waves; wave w owns keys [512w, 512w+512).
// Pass A: QK^T + masked exp -> row-sums (mask bits cached in 4 VGPRs).
// Pass B: recompute, normalize fp32, nt-store attn, PV via 1KB/wave LDS staging.
template<bool PRE>
__global__ __launch_bounds__(256, 4)
void attn_main(const float* __restrict__ qf, const float* __restrict__ kf,
               const float* __restrict__ vf, const int* __restrict__ mask,
               const unsigned short* __restrict__ qb,
               const unsigned short* __restrict__ kbp,
               const unsigned short* __restrict__ vt,
               const unsigned* __restrict__ bits32,
               float* __restrict__ out, float* __restrict__ attn)
{
  __shared__ __align__(16) unsigned char Pv[4][1024];   // per-wave P staging (16 rows x 32 keys bf16)
  __shared__ __align__(16) float Ored[4][16][64];       // per-wave partial O
  __shared__ float rpart[4][16];
  __shared__ float rinv16[16];

  const int tid  = threadIdx.x;
  const int wave = tid >> 6;
  const int lane = tid & 63;
  const int l15  = lane & 15;
  const int lg   = lane >> 4;

  const int bh    = blockIdx.x >> 7;
  const int qbase = (blockIdx.x & 127) << 4;
  const int wbase = wave << 9;                          // this wave's first key

  // Q fragments (B operand of swapped QK^T): col q = l15, k-elems = d
  bf16x8 qfr0, qfr1;
  {
    const long qrow = (long)(bh * Ss + qbase + l15) * Dd + lg * 8;
    if (PRE) {
      qfr0 = *reinterpret_cast<const bf16x8*>(qb + qrow);
      qfr1 = *reinterpret_cast<const bf16x8*>(qb + qrow + 32);
    } else {
      qfr0 = cvt8(qf + qrow);
      qfr1 = cvt8(qf + qrow + 32);
    }
  }

  const long mrowQ = (long)(bh * Ss + qbase + l15) * Ss;  // lane's q-row element base

  unsigned mpack[4] = {0u, 0u, 0u, 0u};
  float psum = 0.f;

  // ---- Pass A: row sums ----
  for (int it = 0; it < 16; ++it) {
    const int key0 = wbase + (it << 5);
    const long kr0 = (long)(bh * Ss + key0 + l15) * Dd + lg * 8;
    bf16x8 kA0, kA1, kB0, kB1;
    if (PRE) {
      kA0 = *reinterpret_cast<const bf16x8*>(kbp + kr0);
      kA1 = *reinterpret_cast<const bf16x8*>(kbp + kr0 + 32);
      kB0 = *reinterpret_cast<const bf16x8*>(kbp + kr0 + 16 * Dd);
      kB1 = *reinterpret_cast<const bf16x8*>(kbp + kr0 + 16 * Dd + 32);
    } else {
      kA0 = cvt8(kf + kr0);        kA1 = cvt8(kf + kr0 + 32);
      kB0 = cvt8(kf + kr0 + 16 * Dd); kB1 = cvt8(kf + kr0 + 16 * Dd + 32);
    }
    unsigned mm;
    if (PRE) {
      const unsigned w32 = bits32[(unsigned long long)(mrowQ + key0) >> 5];
      mm = ((w32 >> (lg * 4)) & 0xFu) | (((w32 >> (16 + lg * 4)) & 0xFu) << 4);
    } else {
      const int4 m0 = *reinterpret_cast<const int4*>(mask + mrowQ + key0 + lg * 4);
      const int4 m1 = *reinterpret_cast<const int4*>(mask + mrowQ + key0 + 16 + lg * 4);
      mm = (m0.x ? 1u : 0u) | (m0.y ? 2u : 0u) | (m0.z ? 4u : 0u) | (m0.w ? 8u : 0u)
         | (m1.x ? 16u : 0u) | (m1.y ? 32u : 0u) | (m1.z ? 64u : 0u) | (m1.w ? 128u : 0u);
    }
    mpack[it >> 2] |= mm << ((it & 3) << 3);
    f32x4 aA = {0.f, 0.f, 0.f, 0.f}, aB = {0.f, 0.f, 0.f, 0.f};
    aA = __builtin_amdgcn_mfma_f32_16x16x32_bf16(kA0, qfr0, aA, 0, 0, 0);
    aA = __builtin_amdgcn_mfma_f32_16x16x32_bf16(kA1, qfr1, aA, 0, 0, 0);
    aB = __builtin_amdgcn_mfma_f32_16x16x32_bf16(kB0, qfr0, aB, 0, 0, 0);
    aB = __builtin_amdgcn_mfma_f32_16x16x32_bf16(kB1, qfr1, aB, 0, 0, 0);
    psum += ((mm &   1u) ? __expf(aA[0] * SCALE) : 0.f)
          + ((mm &   2u) ? __expf(aA[1] * SCALE) : 0.f)
          + ((mm &   4u) ? __expf(aA[2] * SCALE) : 0.f)
          + ((mm &   8u) ? __expf(aA[3] * SCALE) : 0.f)
          + ((mm &  16u) ? __expf(aB[0] * SCALE) : 0.f)
          + ((mm &  32u) ? __expf(aB[1] * SCALE) : 0.f)
          + ((mm &  64u) ? __expf(aB[2] * SCALE) : 0.f)
          + ((mm & 128u) ? __expf(aB[3] * SCALE) : 0.f);
  }

  psum += __shfl_xor(psum, 16);
  psum += __shfl_xor(psum, 32);
  if (lane < 16) rpart[wave][l15] = psum;
  __syncthreads();
  if (tid < 16) {
    const float t = rpart[0][tid] + rpart[1][tid] + rpart[2][tid] + rpart[3][tid];
    rinv16[tid] = (t > 0.f) ? (1.f / t) : 0.f;
  }
  __syncthreads();
  const float inv = rinv16[l15];

  // ---- Pass B: recompute, write attn, PV accumulate ----
  unsigned char* myPv = &Pv[wave][0];
  const int swz = (l15 & 3) << 4;                      // XOR swizzle within 64B row
  float* arow = attn + (long)(bh * Ss + qbase + l15) * Ss;
  const unsigned short* vtb = PRE ? (vt + (long)(bh * Dd) * Ss) : nullptr;

  f32x4 ob0 = {0.f,0.f,0.f,0.f}, ob1 = {0.f,0.f,0.f,0.f};
  f32x4 ob2 = {0.f,0.f,0.f,0.f}, ob3 = {0.f,0.f,0.f,0.f};

  for (int it = 0; it < 16; ++it) {
    const int key0 = wbase + (it << 5);
    const long kr0 = (long)(bh * Ss + key0 + l15) * Dd + lg * 8;
    bf16x8 kA0, kA1, kB0, kB1;
    if (PRE) {
      kA0 = *reinterpret_cast<const bf16x8*>(kbp + kr0);
      kA1 = *reinterpret_cast<const bf16x8*>(kbp + kr0 + 32);
      kB0 = *reinterpret_cast<const bf16x8*>(kbp + kr0 + 16 * Dd);
      kB1 = *reinterpret_cast<const bf16x8*>(kbp + kr0 + 16 * Dd + 32);
    } else {
      kA0 = cvt8(kf + kr0);        kA1 = cvt8(kf + kr0 + 32);
      kB0 = cvt8(kf + kr0 + 16 * Dd); kB1 = cvt8(kf + kr0 + 16 * Dd + 32);
    }
    f32x4 aA = {0.f, 0.f, 0.f, 0.f}, aB = {0.f, 0.f, 0.f, 0.f};
    aA = __builtin_amdgcn_mfma_f32_16x16x32_bf16(kA0, qfr0, aA, 0, 0, 0);
    aA = __builtin_amdgcn_mfma_f32_16x16x32_bf16(kA1, qfr1, aA, 0, 0, 0);
    aB = __builtin_amdgcn_mfma_f32_16x16x32_bf16(kB0, qfr0, aB, 0, 0, 0);
    aB = __builtin_amdgcn_mfma_f32_16x16x32_bf16(kB1, qfr1, aB, 0, 0, 0);

    const unsigned mm = (mpack[it >> 2] >> ((it & 3) << 3)) & 0xFFu;
    const float p0 = (mm &   1u) ? __expf(aA[0] * SCALE) * inv : 0.f;
    const float p1 = (mm &   2u) ? __expf(aA[1] * SCALE) * inv : 0.f;
    const float p2 = (mm &   4u) ? __expf(aA[2] * SCALE) * inv : 0.f;
    const float p3 = (mm &   8u) ? __expf(aA[3] * SCALE) * inv : 0.f;
    const float p4 = (mm &  16u) ? __expf(aB[0] * SCALE) * inv : 0.f;
    const float p5 = (mm &  32u) ? __expf(aB[1] * SCALE) * inv : 0.f;
    const float p6 = (mm &  64u) ? __expf(aB[2] * SCALE) * inv : 0.f;
    const float p7 = (mm & 128u) ? __expf(aB[3] * SCALE) * inv : 0.f;

    f32x4 s0; s0[0] = p0; s0[1] = p1; s0[2] = p2; s0[3] = p3;
    f32x4 s1; s1[0] = p4; s1[1] = p5; s1[2] = p6; s1[3] = p7;
    __builtin_nontemporal_store(s0, reinterpret_cast<f32x4*>(arow + key0 + lg * 4));
    __builtin_nontemporal_store(s1, reinterpret_cast<f32x4*>(arow + key0 + 16 + lg * 4));

    uint2 w0, w1;
    w0.x = (unsigned)f2bf(p0) | ((unsigned)f2bf(p1) << 16);
    w0.y = (unsigned)f2bf(p2) | ((unsigned)f2bf(p3) << 16);
    w1.x = (unsigned)f2bf(p4) | ((unsigned)f2bf(p5) << 16);
    w1.y = (unsigned)f2bf(p6) | ((unsigned)f2bf(p7) << 16);
    *reinterpret_cast<uint2*>(myPv + (l15 << 6) + (((lg << 3)      ) ^ swz)) = w0;
    *reinterpret_cast<uint2*>(myPv + (l15 << 6) + ((32 + (lg << 3)) ^ swz)) = w1;

    // afrag: row q = l15, keys key0 + lg*8 .. +8 (cross-lane within wave; lgkmcnt ordering)
    const bf16x8 af = *reinterpret_cast<const bf16x8*>(myPv + (l15 << 6) + (((lg << 4)) ^ swz));

    if (PRE) {
      const unsigned short* vp = vtb + key0 + lg * 8;
      ob0 = __builtin_amdgcn_mfma_f32_16x16x32_bf16(af, *reinterpret_cast<const bf16x8*>(vp + (long)(l15)      * Ss), ob0, 0, 0, 0);
      ob1 = __builtin_amdgcn_mfma_f32_16x16x32_bf16(af, *reinterpret_cast<const bf16x8*>(vp + (long)(16 + l15) * Ss), ob1, 0, 0, 0);
      ob2 = __builtin_amdgcn_mfma_f32_16x16x32_bf16(af, *reinterpret_cast<const bf16x8*>(vp + (long)(32 + l15) * Ss), ob2, 0, 0, 0);
      ob3 = __builtin_amdgcn_mfma_f32_16x16x32_bf16(af, *reinterpret_cast<const bf16x8*>(vp + (long)(48 + l15) * Ss), ob3, 0, 0, 0);
    } else {
      const float* vp = vf + (long)(bh * Ss + key0 + lg * 8) * Dd + l15;
      bf16x8 b0, b1, b2, b3;
#pragma unroll
      for (int e = 0; e < 8; ++e) {
        b0[e] = (short)f2bf(vp[e * Dd]);
        b1[e] = (short)f2bf(vp[e * Dd + 16]);
        b2[e] = (short)f2bf(vp[e * Dd + 32]);
        b3[e] = (short)f2bf(vp[e * Dd + 48]);
      }
      ob0 = __builtin_amdgcn_mfma_f32_16x16x32_bf16(af, b0, ob0, 0, 0, 0);
      ob1 = __builtin_amdgcn_mfma_f32_16x16x32_bf16(af, b1, ob1, 0, 0, 0);
      ob2 = __builtin_amdgcn_mfma_f32_16x16x32_bf16(af, b2, ob2, 0, 0, 0);
      ob3 = __builtin_amdgcn_mfma_f32_16x16x32_bf16(af, b3, ob3, 0, 0, 0);
    }
  }

  // ---- O reduce across waves + coalesced out write ----
#pragma unroll
  for (int r = 0; r < 4; ++r) {
    Ored[wave][(lg << 2) + r][l15]      = ob0[r];
    Ored[wave][(lg << 2) + r][16 + l15] = ob1[r];
    Ored[wave][(lg << 2) + r][32 + l15] = ob2[r];
    Ored[wave][(lg << 2) + r][48 + l15] = ob3[r];
  }
  __syncthreads();
  {
    const f32x4* Op = reinterpret_cast<const f32x4*>(&Ored[0][0][0]);
    f32x4 t = Op[tid];
    t += Op[256 + tid];
    t += Op[512 + tid];
    t += Op[768 + tid];
    __builtin_nontemporal_store(t, reinterpret_cast<f32x4*>(out + (long)(bh * Ss + qbase) * Dd + (tid << 2)));
  }
}

extern "C" void kernel_launch(void* const* d_in, const int* in_sizes, int n_in,
                              void* d_out, int out_size, void* d_ws, size_t ws_size,
                              hipStream_t stream)
{
  const float* q    = (const float*)d_in[0];
  const float* k    = (const float*)d_in[1];
  const float* v    = (const float*)d_in[2];
  const int*   mask = (const int*)d_in[3];
  float* out  = (float*)d_out;
  float* attn = out + QKV_ELEMS;

  const size_t bf16_bytes = (size_t)QKV_ELEMS * 2 * 3;          // qb + kb + vt
  const size_t bits_bytes = (size_t)(MASK_ELEMS >> 3);          // 32 MiB
  const size_t need = bf16_bytes + bits_bytes;
  if (ws_size >= need) {
    unsigned short* qb = (unsigned short*)d_ws;
    unsigned short* kb = qb + QKV_ELEMS;
    unsigned short* vt = kb + QKV_ELEMS;
    unsigned long long* bits = (unsigned long long*)((char*)d_ws + bf16_bytes);
    hipLaunchKernelGGL(bitpack, dim3(2048), dim3(256), 0, stream, mask, bits);
    hipLaunchKernelGGL(cvt_qk, dim3((unsigned)(QKV_ELEMS / 1024)), dim3(256), 0, stream, q, k, qb, kb);
    hipLaunchKernelGGL(cvt_vt, dim3(BH * 32), dim3(256), 0, stream, v, vt);
    hipLaunchKernelGGL((attn_main<true>), dim3(BH * 128), dim3(256), 0, stream,
                       q, k, v, mask, qb, kb, vt, (const unsigned*)bits, out, attn);
  } else {
    hipLaunchKernelGGL((attn_main<false>), dim3(BH * 128), dim3(256), 0, stream,
                       q, k, v, mask, nullptr, nullptr, nullptr, nullptr, out, attn);
  }
}